// Round 10
// baseline (206.570 us; speedup 1.0000x reference)
//
#include <hip/hip_runtime.h>

typedef __attribute__((ext_vector_type(8))) short short8;
typedef __attribute__((ext_vector_type(4))) float f32x4;
typedef __attribute__((ext_vector_type(16))) float f32x16;

__device__ __forceinline__ float bf2f(unsigned short u) {
    union { unsigned int i; float f; } c; c.i = ((unsigned int)u) << 16; return c.f;
}
__device__ __forceinline__ unsigned short f2bf(float f) {   // RNE
    union { float f; unsigned int i; } c; c.f = f;
    unsigned int u = c.i;
    return (unsigned short)((u + 0x7fffu + ((u >> 16) & 1u)) >> 16);
}

// async global->LDS, 16B per lane. LDS dest = wave-uniform base + lane*16.
__device__ __forceinline__ void glds16(const void* g, void* l) {
    __builtin_amdgcn_global_load_lds(
        (const __attribute__((address_space(1))) unsigned int*)g,
        (__attribute__((address_space(3))) unsigned int*)l, 16, 0, 0);
}

union i4s8 { int4 i; short8 s; };

// SCL = (1/sqrt(64)) * log2(e), folded into q at gemm_qkv epilogue.
#define SCL_F 0.18033688011112042f

// ---------------------------------------------------------------------------
// prep: fp32->bf16 for x / qkv_w / proj_w. Grid-stride, 2048 blocks.
// ---------------------------------------------------------------------------
__global__ __launch_bounds__(256) void prep(
    const float* __restrict__ x, const float* __restrict__ qkv_w,
    const float* __restrict__ proj_w,
    unsigned short* __restrict__ xb, unsigned short* __restrict__ qwb,
    unsigned short* __restrict__ pwb)
{
    const int TX = 1048576, TQ = 786432, TP = 262144;   // float4 counts
    const int total = TX + TQ + TP;
    for (int i = blockIdx.x * 256 + threadIdx.x; i < total; i += 2048 * 256) {
        const float* src; unsigned short* dst; int j;
        if (i < TX)           { src = x;      dst = xb;  j = i; }
        else if (i < TX + TQ) { src = qkv_w;  dst = qwb; j = i - TX; }
        else                  { src = proj_w; dst = pwb; j = i - TX - TQ; }
        float4 v = ((const float4*)src)[j];
        ushort4 o;
        o.x = f2bf(v.x); o.y = f2bf(v.y); o.z = f2bf(v.z); o.w = f2bf(v.w);
        ((ushort4*)dst)[j] = o;
    }
}

// ---------------------------------------------------------------------------
// QKV GEMM (NT) + fused bias + RMSNorm + segmented RoPE epilogue.
// 128x128 tile, BK=64, 16x16x32 MFMA, 4 waves 2x2.   (round-9 validated)
// ---------------------------------------------------------------------------
__global__ __launch_bounds__(256) void gemm_qkv(
    const unsigned short* __restrict__ A,
    const unsigned short* __restrict__ W,
    const float* __restrict__ bias,
    const float* __restrict__ qn_w, const float* __restrict__ kn_w,
    unsigned short* __restrict__ qb, unsigned short* __restrict__ kb,
    unsigned short* __restrict__ vt)
{
    __shared__ unsigned short pool[128 * 136];
    const int tid = threadIdx.x;
    const int w = tid >> 6, l = tid & 63, quad = l >> 4, low = l & 15;
    const int m0 = blockIdx.y * 128, n0 = blockIdx.x * 128;
    const int wm = w >> 1, wn = w & 1;
    const int K = 1024;

    f32x4 acc[4][4];
#pragma unroll
    for (int i = 0; i < 4; i++)
#pragma unroll
        for (int j = 0; j < 4; j++) acc[i][j] = (f32x4){0.f, 0.f, 0.f, 0.f};

    const int r1 = tid >> 3, p1 = tid & 7, c1 = p1 ^ (r1 & 7);
    const unsigned short* ga = A + (size_t)(m0 + r1) * K + c1 * 8;
    const unsigned short* gw = W + (size_t)(n0 + r1) * K + c1 * 8;
    char* lA = (char*)pool + (w << 10);
    char* lW = (char*)pool + 16384 + (w << 10);

    for (int k0 = 0; k0 < K; k0 += 64) {
        __syncthreads();
        glds16(ga + k0,            lA);
        glds16(ga + k0 + 32 * K,   lA + 4096);
        glds16(ga + k0 + 64 * K,   lA + 8192);
        glds16(ga + k0 + 96 * K,   lA + 12288);
        glds16(gw + k0,            lW);
        glds16(gw + k0 + 32 * K,   lW + 4096);
        glds16(gw + k0 + 64 * K,   lW + 8192);
        glds16(gw + k0 + 96 * K,   lW + 12288);
        __syncthreads();
#pragma unroll
        for (int ks = 0; ks < 2; ks++) {
            short8 af[4], wf[4];
#pragma unroll
            for (int i = 0; i < 4; i++) {
                const int ra = wm * 64 + i * 16 + low;
                af[i] = *(const short8*)&pool[ra * 64 + ((ks * 4 + quad) ^ (ra & 7)) * 8];
                const int rw = wn * 64 + i * 16 + low;
                wf[i] = *(const short8*)&pool[8192 + rw * 64 + ((ks * 4 + quad) ^ (rw & 7)) * 8];
            }
#pragma unroll
            for (int i = 0; i < 4; i++)
#pragma unroll
                for (int j = 0; j < 4; j++)
                    acc[i][j] = __builtin_amdgcn_mfma_f32_16x16x32_bf16(
                        af[i], wf[j], acc[i][j], 0, 0, 0);
        }
    }

    const int colbase = n0 + wn * 64;
    const int t3 = n0 >> 10;
    const int hh = (colbase & 1023) >> 6;

    if (t3 == 2) {
        __syncthreads();
#pragma unroll
        for (int i = 0; i < 4; i++)
#pragma unroll
            for (int j = 0; j < 4; j++) {
                const int c = wn * 64 + j * 16 + low;
                const float bv = bias[n0 + c];
#pragma unroll
                for (int reg = 0; reg < 4; reg++) {
                    const int r = wm * 64 + i * 16 + quad * 4 + reg;
                    pool[c * 136 + r] = f2bf(acc[i][j][reg] + bv);
                }
            }
        __syncthreads();
        const int b_ = m0 >> 11, nbase = m0 & 2047;
        const int rch = (tid & 15) * 8;
#pragma unroll
        for (int p = 0; p < 8; p++) {
            const int c = (tid >> 4) + p * 16;
            const int gc = n0 + c;
            const int h2 = (gc & 1023) >> 6, d = gc & 63;
            const short8 vv = *(const short8*)&pool[c * 136 + rch];
            *(short8*)(vt + ((size_t)((b_ * 16 + h2) * 64 + d)) * 2048 + nbase + rch) = vv;
        }
        return;
    }

    const float* nw = (t3 == 0) ? qn_w : kn_w;
    const float wscl = (t3 == 0) ? SCL_F : 1.0f;
    float wv4[4];
#pragma unroll
    for (int j = 0; j < 4; j++) wv4[j] = nw[j * 16 + low] * wscl;
    const float c0 = -2.0f * 13.287712379549449f / 64.0f;
    const float invA = exp2f(c0 * (float)low);
    const float invB = exp2f(c0 * (float)(16 + low));
    unsigned short* dqk = (t3 == 0) ? qb : kb;

#pragma unroll
    for (int i = 0; i < 4; i++) {
#pragma unroll
        for (int reg = 0; reg < 4; reg++) {
            const int gm = m0 + wm * 64 + i * 16 + quad * 4 + reg;
            const int b_ = gm >> 11, npos = gm & 2047;
            float v[4];
#pragma unroll
            for (int j = 0; j < 4; j++)
                v[j] = acc[i][j][reg] + bias[colbase + j * 16 + low];
            float ss = v[0]*v[0] + v[1]*v[1] + v[2]*v[2] + v[3]*v[3];
            ss += __shfl_xor(ss, 1); ss += __shfl_xor(ss, 2);
            ss += __shfl_xor(ss, 4); ss += __shfl_xor(ss, 8);
            const float r = rsqrtf(ss * (1.0f / 64.0f) + 1e-6f);
            float nv[4];
#pragma unroll
            for (int j = 0; j < 4; j++) nv[j] = v[j] * r * wv4[j];
            float o0, o1, o2, o3;
            if (npos < 1536) {
                const float p = (float)((npos < 1024) ? npos : (npos - 1024));
                float sA, cA, sB, cB;
                __sincosf(p * invA, &sA, &cA);
                __sincosf(p * invB, &sB, &cB);
                o0 = nv[0] * cA - nv[2] * sA;
                o1 = nv[1] * cB - nv[3] * sB;
                o2 = nv[2] * cA + nv[0] * sA;
                o3 = nv[3] * cB + nv[1] * sB;
            } else { o0 = nv[0]; o1 = nv[1]; o2 = nv[2]; o3 = nv[3]; }
            unsigned short* drow =
                dqk + ((size_t)(b_ * 16 + hh) * 2048 + npos) * 64 + low;
            drow[0]  = f2bf(o0);
            drow[16] = f2bf(o1);
            drow[32] = f2bf(o2);
            drow[48] = f2bf(o3);
        }
    }
}

// ---------------------------------------------------------------------------
// MFMA flash attention (round-9 validated), 32x32x16, scale pre-folded.
// 1D grid, 1024 blocks: bh = id&31  =>  id%8 == bh%8, so all 32 blocks of a
// (bh, either half) land on one XCD (round-robin dispatch) -> K/V served
// from that XCD's 4MB L2 instead of 8 HBM copies.
// ---------------------------------------------------------------------------
__global__ __launch_bounds__(256, 4) void flash_mfma(
    const unsigned short* __restrict__ qg, const unsigned short* __restrict__ kg,
    const unsigned short* __restrict__ vg, unsigned short* __restrict__ po,
    float* __restrict__ pl)
{
    __shared__ unsigned short Ks[128 * 64];   // [key][d]   rows 128B, 8 chunks
    __shared__ unsigned short Vs[64 * 128];   // [d][key]   rows 256B, 16 chunks

    const int tid = threadIdx.x;
    const int w = tid >> 6, lane = tid & 63, h5 = lane >> 5, l5 = lane & 31;
    const int id = blockIdx.x;
    const int bh = id & 31;
    const int q0 = ((id >> 5) & 15) * 128;
    const int half = id >> 9;

    short8 qf[4];
    {
        const unsigned short* qrow = qg + ((size_t)bh * 2048 + q0 + w * 32 + l5) * 64;
#pragma unroll
        for (int ks = 0; ks < 4; ks++)
            qf[ks] = *(const short8*)(qrow + ks * 16 + h5 * 8);
    }

    f32x16 o0, o1, ls;
#pragma unroll
    for (int i = 0; i < 16; i++) { o0[i] = 0.f; o1[i] = 0.f; ls[i] = 0.f; }
    i4s8 ones; ones.i = make_int4(0x3F803F80, 0x3F803F80, 0x3F803F80, 0x3F803F80);

    const int krr = tid >> 3, kc = (tid & 7) ^ (krr & 7);
    const unsigned short* gk = kg + ((size_t)bh * 2048 + krr) * 64 + kc * 8;
    const int vrr = tid >> 4, vc = (tid & 15) ^ (vrr & 15);
    const unsigned short* gv = vg + ((size_t)bh * 64 + vrr) * 2048 + vc * 8;
    char* lK = (char*)Ks + (w << 10);
    char* lV = (char*)Vs + (w << 10);
    const int kbase = half * 1024;

    for (int kt = 0; kt < 8; kt++) {
        const size_t ko = (size_t)(kbase + kt * 128);
        __syncthreads();
        glds16(gk + ko * 64,         lK);
        glds16(gk + ko * 64 + 2048,  lK + 4096);
        glds16(gk + ko * 64 + 4096,  lK + 8192);
        glds16(gk + ko * 64 + 6144,  lK + 12288);
        glds16(gv + ko,              lV);
        glds16(gv + ko + 32768,      lV + 4096);
        glds16(gv + ko + 65536,      lV + 8192);
        glds16(gv + ko + 98304,      lV + 12288);
        __syncthreads();

#pragma unroll
        for (int kbk = 0; kbk < 4; kbk++) {
            f32x16 s;
#pragma unroll
            for (int i = 0; i < 16; i++) s[i] = 0.f;
            const int krow = kbk * 32 + l5;
#pragma unroll
            for (int ks = 0; ks < 4; ks++) {
                const int ch = (h5 + 2 * ks) ^ (krow & 7);
                const short8 kf = *(const short8*)&Ks[krow * 64 + ch * 8];
                s = __builtin_amdgcn_mfma_f32_32x32x16_bf16(kf, qf[ks], s, 0, 0, 0);
            }
            unsigned int dw[8], pdw[8];
#pragma unroll
            for (int r = 0; r < 8; r++) {
                union { float f; unsigned int u; } a, b;
                a.f = exp2f(s[2 * r]);
                b.f = exp2f(s[2 * r + 1]);
                dw[r] = __builtin_amdgcn_perm(b.u, a.u, 0x07060302u);
            }
#pragma unroll
            for (int r = 0; r < 8; r++) pdw[r] = __shfl_xor((int)dw[r], 32);
            i4s8 f0, f1;
            f0.i.x = h5 ? pdw[2] : dw[0];
            f0.i.y = h5 ? pdw[3] : dw[1];
            f0.i.z = h5 ? dw[2]  : pdw[0];
            f0.i.w = h5 ? dw[3]  : pdw[1];
            f1.i.x = h5 ? pdw[6] : dw[4];
            f1.i.y = h5 ? pdw[7] : dw[5];
            f1.i.z = h5 ? dw[6]  : pdw[4];
            f1.i.w = h5 ? dw[7]  : pdw[5];

            ls = __builtin_amdgcn_mfma_f32_32x32x16_bf16(f0.s, ones.s, ls, 0, 0, 0);
            ls = __builtin_amdgcn_mfma_f32_32x32x16_bf16(f1.s, ones.s, ls, 0, 0, 0);

#pragma unroll
            for (int nb = 0; nb < 2; nb++) {
                const int vrow = nb * 32 + l5;
                const int chb = kbk * 4 + h5;
                const short8 vfa = *(const short8*)&Vs[vrow * 128 + ((chb    ) ^ (vrow & 15)) * 8];
                const short8 vfb = *(const short8*)&Vs[vrow * 128 + ((chb + 2) ^ (vrow & 15)) * 8];
                f32x16& oo = nb ? o1 : o0;
                oo = __builtin_amdgcn_mfma_f32_32x32x16_bf16(f0.s, vfa, oo, 0, 0, 0);
                oo = __builtin_amdgcn_mfma_f32_32x32x16_bf16(f1.s, vfb, oo, 0, 0, 0);
            }
        }
    }

    unsigned short* pob = po + ((size_t)(half * 32 + bh)) * 2048 * 64;
    float* plb = pl + ((size_t)(half * 32 + bh)) * 2048;
#pragma unroll
    for (int r = 0; r < 16; r++) {
        const int qrow = q0 + w * 32 + (r & 3) + 8 * (r >> 2) + 4 * h5;
        pob[(size_t)qrow * 64 + l5]      = f2bf(o0[r]);
        pob[(size_t)qrow * 64 + 32 + l5] = f2bf(o1[r]);
        if (l5 == 0) plb[qrow] = ls[r];
    }
}

// ---------------------------------------------------------------------------
// combine: ao[b][n][h*64+d] = (po0+po1) / (pl0+pl1).   (validated)
// ---------------------------------------------------------------------------
__global__ __launch_bounds__(256) void combine(
    const unsigned short* __restrict__ po, const float* __restrict__ pl,
    unsigned short* __restrict__ ao)
{
    const int g = blockIdx.x * 256 + threadIdx.x;
    const int row = g >> 3;
    const int c8 = (g & 7) * 8;
    const int bh = row >> 11, n = row & 2047;
    const float inv = 1.0f / (pl[row] + pl[65536 + row]);
    const short8 a = *(const short8*)(po + (size_t)row * 64 + c8);
    const short8 b = *(const short8*)(po + 4194304 + (size_t)row * 64 + c8);
    short8 r;
#pragma unroll
    for (int j = 0; j < 8; j++)
        r[j] = (short)f2bf((bf2f((unsigned short)a[j]) + bf2f((unsigned short)b[j])) * inv);
    const int b_ = bh >> 4, h = bh & 15;
    *(short8*)(ao + ((size_t)(b_ * 2048 + n)) * 1024 + h * 64 + c8) = r;
}

// ---------------------------------------------------------------------------
// Output projection, 32x32x16 MFMA (ISOLATION EXPERIMENT: round-8 version).
// Tile 64x64, BK=64, 128 thr (2 waves), grid (16,64) = 1024 blocks. fp32 out.
// ---------------------------------------------------------------------------
__global__ __launch_bounds__(128) void gemm_out(
    const unsigned short* __restrict__ A,
    const unsigned short* __restrict__ W,
    const float* __restrict__ bias,
    float* __restrict__ outp)
{
    __shared__ unsigned short pool[8192];    // As 4096 shorts | Ws 4096 shorts (16 KB)
    const int tid = threadIdx.x;
    const int w = tid >> 6, lane = tid & 63, h5 = lane >> 5, l5 = lane & 31;
    const int m0 = blockIdx.y * 64, n0 = blockIdx.x * 64;
    const int K = 1024;

    f32x16 acc0, acc1;
#pragma unroll
    for (int i = 0; i < 16; i++) { acc0[i] = 0.f; acc1[i] = 0.f; }

    const int rr = tid >> 3, cc = (tid & 7) ^ (rr & 7);
    const unsigned short* ga = A + (size_t)(m0 + rr) * K + cc * 8;
    const unsigned short* gw = W + (size_t)(n0 + rr) * K + cc * 8;
    char* lA = (char*)pool + (w << 10);
    char* lW = (char*)pool + 8192 + (w << 10);

    for (int k0 = 0; k0 < K; k0 += 64) {
        __syncthreads();
        glds16(ga + k0,           lA);
        glds16(ga + k0 + 16 * K,  lA + 2048);
        glds16(ga + k0 + 32 * K,  lA + 4096);
        glds16(ga + k0 + 48 * K,  lA + 6144);
        glds16(gw + k0,           lW);
        glds16(gw + k0 + 16 * K,  lW + 2048);
        glds16(gw + k0 + 32 * K,  lW + 4096);
        glds16(gw + k0 + 48 * K,  lW + 6144);
        __syncthreads();
        const int ra = w * 32 + l5;
#pragma unroll
        for (int ks = 0; ks < 4; ks++) {
            const int ch = (ks << 1) | h5;
            const short8 af  = *(const short8*)&pool[ra * 64 + (ch ^ (ra & 7)) * 8];
            const short8 wf0 = *(const short8*)&pool[4096 + l5 * 64 + (ch ^ (l5 & 7)) * 8];
            const int rw1 = 32 + l5;
            const short8 wf1 = *(const short8*)&pool[4096 + rw1 * 64 + (ch ^ (rw1 & 7)) * 8];
            acc0 = __builtin_amdgcn_mfma_f32_32x32x16_bf16(af, wf0, acc0, 0, 0, 0);
            acc1 = __builtin_amdgcn_mfma_f32_32x32x16_bf16(af, wf1, acc1, 0, 0, 0);
        }
    }

    const float b0 = bias[n0 + l5], b1 = bias[n0 + 32 + l5];
#pragma unroll
    for (int r = 0; r < 16; r++) {
        const int gm = m0 + w * 32 + (r & 3) + 8 * (r >> 2) + 4 * h5;
        outp[(size_t)gm * 1024 + n0 + l5]      = acc0[r] + b0;
        outp[(size_t)gm * 1024 + n0 + 32 + l5] = acc1[r] + b1;
    }
}

// ---------------------------------------------------------------------------
extern "C" void kernel_launch(void* const* d_in, const int* in_sizes, int n_in,
                              void* d_out, int out_size, void* d_ws, size_t ws_size,
                              hipStream_t stream)
{
    const float* x      = (const float*)d_in[0];
    const float* qkv_w  = (const float*)d_in[1];
    const float* qkv_b  = (const float*)d_in[2];
    const float* qn_w   = (const float*)d_in[3];
    const float* kn_w   = (const float*)d_in[4];
    const float* proj_w = (const float*)d_in[5];
    const float* proj_b = (const float*)d_in[6];

    char* base = (char*)d_ws;
    unsigned short* pwb = (unsigned short*)(base + 256);// 2 MB
    unsigned short* qb  = pwb + 1048576;                // 8 MB
    unsigned short* kb  = qb  + 4194304;                // 8 MB
    unsigned short* vt  = kb  + 4194304;                // 8 MB
    unsigned short* ao  = vt  + 4194304;                // 8 MB
    unsigned short* xb  = ao  + 4194304;                // 8 MB  (dead after gemm_qkv)
    unsigned short* qwb = xb  + 4194304;                // 6 MB  (dead after gemm_qkv)
    unsigned short* po  = xb;                           // 16 MB (overlays xb+qwb+2MB)
    float* pl           = (float*)(po + 8388608);       // 512 KB

    prep<<<2048, 256, 0, stream>>>(x, qkv_w, proj_w, xb, qwb, pwb);

    gemm_qkv<<<dim3(24, 32), 256, 0, stream>>>(xb, qwb, qkv_b, qn_w, kn_w,
                                               qb, kb, vt);

    flash_mfma<<<1024, 256, 0, stream>>>(qb, kb, vt, po, pl);

    combine<<<2048, 256, 0, stream>>>(po, pl, ao);

    gemm_out<<<dim3(16, 64), 128, 0, stream>>>(ao, pwb, proj_b, (float*)d_out);
}